// Round 11
// baseline (153.187 us; speedup 1.0000x reference)
//
#include <hip/hip_runtime.h>
#include <hip/hip_bf16.h>
#include <math.h>

#define C_CLS   1024
#define NPROXY  8
#define ALLNUM  8192
#define DIM     512
#define TOPK    410
#define LAM     0.3f
#define BATCH   2048

#define BAND_CAP_BLK 40     // per-row per-256-col-tile band capacity (mean ~9, +10 sigma)
#define ROW_CAP      512    // per-row total band capacity (mean ~287)
#define GCAP         64

typedef __bf16 bf16x8 __attribute__((ext_vector_type(8)));
typedef float floatx4 __attribute__((ext_vector_type(4)));
typedef unsigned short ushort_t;

// ws layout (float offsets)
#define WS_RNORM 0                       // 8192
#define WS_SIG   8192                    // 2048
#define WS_LP    10240                   // 2048
#define WS_RP    12288                   // 2048 (reg_part uses 128)
#define WS_CNT   14336                   // 2048 u32 (band count per row)
#define WS_NDEF  16384                   // 2048 u32 (definite count per row)
#define WS_FLAG  18432                   // 2048 u32 (overflow -> fallback)
#define WS_CLS   20480                   // 2048*1024 f32 class sums (definite+tgt)
#define WS_BVAL  (WS_CLS + 2048*1024)    // 2048*512 f32 band values
#define WS_BCOL  (WS_BVAL + 2048*512)    // 2048*512 u16 band cols
#define WS_ABF   (WS_BCOL + 2048*256)    // 2048*512 bf16
#define WS_PBF   (WS_ABF + 524288)       // 8192*512 bf16
#define WS_STBF  (WS_PBF + 2097152)      // 1024*512 bf16
#define WS_MX    (WS_STBF + 262144)      // 8192*8 f32 lse partial max
#define WS_SE    (WS_MX + 65536)         // 8192*8 f32 lse partial sumexp
#define WS_DIAG  (WS_SE + 65536)         // 8192 f32 diag logits

// ---------------- helpers ----------------------------------------------------
__device__ inline float block_reduce(float v, int is_max, float* red, int t) {
    #pragma unroll
    for (int o = 32; o > 0; o >>= 1) {
        float w = __shfl_down(v, o);
        v = is_max ? fmaxf(v, w) : (v + w);
    }
    __syncthreads();
    if ((t & 63) == 0) red[t >> 6] = v;
    __syncthreads();
    float r = is_max ? fmaxf(fmaxf(red[0], red[1]), fmaxf(red[2], red[3]))
                     : (red[0] + red[1] + red[2] + red[3]);
    __syncthreads();
    return r;
}

__device__ inline ushort_t f2bf(float f) {   // RNE float->bf16
    unsigned u = __float_as_uint(f);
    return (ushort_t)((u + 0x7FFFu + ((u >> 16) & 1u)) >> 16);
}

__device__ inline float bf2f(ushort_t u) {
    return __uint_as_float(((unsigned)u) << 16);
}

__device__ inline void ld_g2l_16(const void* g, void* l) {
    __builtin_amdgcn_global_load_lds(
        (const __attribute__((address_space(1))) unsigned int*)g,
        (__attribute__((address_space(3))) unsigned int*)l,
        16, 0, 0);
}

__device__ inline unsigned f2ord(float f) {  // monotone float->uint
    unsigned u = __float_as_uint(f);
    return (u & 0x80000000u) ? ~u : (u | 0x80000000u);
}

// ---- K1: wide-load prep -----------------------------------------------------
//   bx 0..63      : colnorm+buildSt fused, 128 cols/block, float4 loads
//   bx 64..1087   : convA (r2-verbatim, float4)
//   bx 1088..2111 : tconv 32x128 tiles, float4 loads, LDS transpose
//   bx 2112       : zero aux
__global__ __launch_bounds__(256) void k_prep1(const float* __restrict__ P,
                                               const float* __restrict__ input,
                                               float* __restrict__ rnorm,
                                               float* __restrict__ rowsig,
                                               ushort_t* __restrict__ Abf,
                                               ushort_t* __restrict__ Pbf,
                                               ushort_t* __restrict__ Stbf,
                                               unsigned* __restrict__ zaux) {
    __shared__ __align__(16) float smem[32 * 132];   // 16.9 KB union
    int bx = blockIdx.x, t = threadIdx.x;
    if (bx < 64) {
        // ---- colnorm + buildSt: cols c0..c0+127 (= 16 classes) --------------
        float* sacc = smem;             // [8][32][4] = 1024 f
        float* s_rn = smem + 1024;      // [128]
        int c0 = bx * 128;
        int q = t & 31, rg = t >> 5;
        float a0 = 0.f, a1 = 0.f, a2 = 0.f, a3 = 0.f;
        for (int k = 0; k < 64; ++k) {
            float4 v = *(const float4*)&P[(size_t)(rg + k * 8) * ALLNUM + c0 + q * 4];
            a0 += v.x * v.x; a1 += v.y * v.y; a2 += v.z * v.z; a3 += v.w * v.w;
        }
        float* dst = &sacc[(rg * 32 + q) * 4];
        dst[0] = a0; dst[1] = a1; dst[2] = a2; dst[3] = a3;
        __syncthreads();
        if (t < 32) {
            float t0 = 0.f, t1 = 0.f, t2 = 0.f, t3 = 0.f;
            #pragma unroll
            for (int g = 0; g < 8; ++g) {
                const float* s = &sacc[(g * 32 + t) * 4];
                t0 += s[0]; t1 += s[1]; t2 += s[2]; t3 += s[3];
            }
            float4 r;
            r.x = 1.0f / fmaxf(sqrtf(t0), 1e-12f);
            r.y = 1.0f / fmaxf(sqrtf(t1), 1e-12f);
            r.z = 1.0f / fmaxf(sqrtf(t2), 1e-12f);
            r.w = 1.0f / fmaxf(sqrtf(t3), 1e-12f);
            *(float4*)&rnorm[c0 + t * 4] = r;
            s_rn[t * 4]     = r.x;
            s_rn[t * 4 + 1] = r.y;
            s_rn[t * 4 + 2] = r.z;
            s_rn[t * 4 + 3] = r.w;
        }
        __syncthreads();
        // buildSt: St[bx*16+cc][d] = sum_n P[d][c0+cc*8+n]*rn[n]  (L2-hot reads)
        int cc = t & 15, dg = t >> 4;   // dg 0..15 -> d-range dg*32..+31
        float rn[8];
        #pragma unroll
        for (int n = 0; n < 8; ++n) rn[n] = s_rn[cc * 8 + n];
        int dbase = dg * 32;
        #pragma unroll
        for (int c4 = 0; c4 < 8; ++c4) {
            ushort4 o;
            #pragma unroll
            for (int dd = 0; dd < 4; ++dd) {
                int d = dbase + c4 * 4 + dd;
                float4 x = *(const float4*)&P[(size_t)d * ALLNUM + c0 + cc * 8];
                float4 y = *(const float4*)&P[(size_t)d * ALLNUM + c0 + cc * 8 + 4];
                float v = x.x * rn[0] + x.y * rn[1] + x.z * rn[2] + x.w * rn[3] +
                          y.x * rn[4] + y.y * rn[5] + y.z * rn[6] + y.w * rn[7];
                ((ushort_t*)&o)[dd] = f2bf(v);
            }
            *(ushort4*)&Stbf[(size_t)(bx * 16 + cc) * DIM + dbase + c4 * 4] = o;
        }
    } else if (bx < 64 + 1024) {
        // ---- convA: input fp32 -> bf16 + row norms (block = exactly 2 rows) -
        float* cred = smem;
        int a = bx - 64;
        int idx = a * 256 + t;
        float4 v = ((const float4*)input)[idx];
        ushort4 o;
        o.x = f2bf(v.x); o.y = f2bf(v.y); o.z = f2bf(v.z); o.w = f2bf(v.w);
        ((ushort4*)Abf)[idx] = o;
        float sq = v.x * v.x + v.y * v.y + v.z * v.z + v.w * v.w;
        #pragma unroll
        for (int off = 32; off > 0; off >>= 1) sq += __shfl_down(sq, off);
        int lane = t & 63, w = t >> 6;
        if (lane == 0) cred[w] = sq;
        __syncthreads();
        if (t == 0) {
            rowsig[2 * a]     = sqrtf(cred[0] + cred[1]);
            rowsig[2 * a + 1] = sqrtf(cred[2] + cred[3]);
        }
    } else if (bx < 64 + 1024 + 1024) {
        // ---- tconv: P [512][8192] fp32 -> Pbf [8192][512] bf16, 32x128 tiles
        float* tile = smem;             // [32][132]
        int id = bx - 1088;             // 0..1023
        int r0 = (id >> 6) * 32;        // 16 row-tiles
        int c0 = (id & 63) * 128;       // 64 col-tiles
        #pragma unroll
        for (int pass = 0; pass < 4; ++pass) {
            int row = pass * 8 + (t >> 5);
            int cq = t & 31;
            float4 v = *(const float4*)&P[(size_t)(r0 + row) * ALLNUM + c0 + cq * 4];
            float* td = &tile[row * 132 + cq * 4];
            td[0] = v.x; td[1] = v.y; td[2] = v.z; td[3] = v.w;
        }
        __syncthreads();
        int c = t >> 1, dh = (t & 1) * 16;
        #pragma unroll
        for (int j = 0; j < 4; ++j) {
            ushort4 o;
            #pragma unroll
            for (int e = 0; e < 4; ++e)
                ((ushort_t*)&o)[e] = f2bf(tile[(dh + j * 4 + e) * 132 + c]);
            *(ushort4*)&Pbf[(size_t)(c0 + c) * DIM + r0 + dh + j * 4] = o;
        }
    } else {
        // zero cnt/ndef/flag (contiguous 3*2048 u32)
        for (int i = t; i < 3 * 2048; i += 256) zaux[i] = 0u;
    }
}

// ---- K2 (r10-verbatim): 2-phase dbuf gemms (direct mapping) -----------------
//      gemm0 (bx 0..255):  256x256 sim tiles + binning epilogue
//      gemm1 (bx 256..511): 256x128 tiles, fused LSE partials epilogue
__global__ __launch_bounds__(512, 2) void k_gemms(const ushort_t* __restrict__ Abf,
                                                  const ushort_t* __restrict__ Pbf,
                                                  const ushort_t* __restrict__ Stbf,
                                                  const float* __restrict__ rnorm,
                                                  const float* __restrict__ rowsig,
                                                  const int* __restrict__ target,
                                                  float* __restrict__ g_cls,
                                                  float* __restrict__ g_bval,
                                                  ushort_t* __restrict__ g_bcol,
                                                  unsigned* __restrict__ g_cnt,
                                                  unsigned* __restrict__ g_ndef,
                                                  unsigned* __restrict__ g_flag,
                                                  float* __restrict__ g_mx,
                                                  float* __restrict__ g_se,
                                                  float* __restrict__ g_diag) {
    __shared__ __align__(16) ushort_t smem[65536];   // 128 KB: dbuf A+B
    int bx = blockIdx.x, t = threadIdx.x;
    int w = t >> 6, lane = t & 63;
    int ml = lane & 15, q4 = lane >> 4;

    if (bx < 256) {
        // ================= gemm0: sim = Abf(2048x512) @ Pbf(8192x512)^T ======
        int bi = (bx >> 5) * 256, bj = (bx & 31) * 256;
        int wm = w >> 2, wn = w & 3;     // 2M x 4N, per-wave 128x64
        ushort_t* sA0 = smem;            // [256][64]
        ushort_t* sB0 = smem + 16384;
        ushort_t* sA1 = smem + 32768;
        ushort_t* sB1 = smem + 49152;

        floatx4 acc[8][4];
        #pragma unroll
        for (int mf = 0; mf < 8; ++mf)
            #pragma unroll
            for (int nf = 0; nf < 4; ++nf)
                acc[mf][nf] = (floatx4){0.f, 0.f, 0.f, 0.f};

        #define STAGE0(sa, sb, k0) do {                                        \
            _Pragma("unroll")                                                  \
            for (int it = 0; it < 4; ++it) {                                   \
                int c = w * 256 + it * 64 + lane;                              \
                int m = c >> 3, s = c & 7, qq = s ^ (m & 7);                   \
                ld_g2l_16(Abf + ((size_t)(bi + m) << 9) + (k0) + qq * 8,       \
                          &(sa)[c * 8]);                                       \
            }                                                                  \
            _Pragma("unroll")                                                  \
            for (int it = 0; it < 4; ++it) {                                   \
                int c = w * 256 + it * 64 + lane;                              \
                int m = c >> 3, s = c & 7, qq = s ^ (m & 7);                   \
                ld_g2l_16(Pbf + ((size_t)(bj + m) << 9) + (k0) + qq * 8,       \
                          &(sb)[c * 8]);                                       \
            }                                                                  \
        } while (0)

        STAGE0(sA0, sB0, 0);
        __syncthreads();
        #pragma unroll
        for (int tt = 0; tt < 8; ++tt) {
            ushort_t* cA = (tt & 1) ? sA1 : sA0;
            ushort_t* cB = (tt & 1) ? sB1 : sB0;
            if (tt < 7) {
                if (tt & 1) STAGE0(sA0, sB0, (tt + 1) * 64);
                else        STAGE0(sA1, sB1, (tt + 1) * 64);
            }
            #pragma unroll
            for (int kk = 0; kk < 2; ++kk) {
                bf16x8 bfr[4];
                #pragma unroll
                for (int nf = 0; nf < 4; ++nf) {
                    int n = wn * 64 + nf * 16 + ml;
                    int s = (kk * 4 + q4) ^ (n & 7);
                    bfr[nf] = *(const bf16x8*)&cB[n * 64 + s * 8];
                }
                #pragma unroll
                for (int mf = 0; mf < 8; ++mf) {
                    int m = wm * 128 + mf * 16 + ml;
                    int s = (kk * 4 + q4) ^ (m & 7);
                    bf16x8 af = *(const bf16x8*)&cA[m * 64 + s * 8];
                    #pragma unroll
                    for (int nf = 0; nf < 4; ++nf)
                        acc[mf][nf] = __builtin_amdgcn_mfma_f32_16x16x32_bf16(
                            af, bfr[nf], acc[mf][nf], 0, 0, 0);
                }
            }
            __syncthreads();
        }
        #undef STAGE0

        // ---- fused binning epilogue (LDS aliased over staging buffers) ------
        unsigned char* sb8 = (unsigned char*)smem;
        float*    e_cls = (float*)sb8;                  // [256][32] f32 (32768 B)
        float*    e_bv  = (float*)(sb8 + 32768);        // [256][40] f32 (40960 B)
        ushort_t* e_bc  = (ushort_t*)(sb8 + 73728);     // [256][40] u16 (20480 B)
        unsigned* e_cnt = (unsigned*)(sb8 + 94208);     // [256] u32
        unsigned* e_nd  = (unsigned*)(sb8 + 95232);     // [256] u32

        #pragma unroll
        for (int i = t; i < 8192; i += 512) e_cls[i] = 0.f;
        if (t < 256) { e_cnt[t] = 0u; e_nd[t] = 0u; }
        __syncthreads();

        #pragma unroll
        for (int mf = 0; mf < 8; ++mf) {
            int rl0 = wm * 128 + mf * 16 + q4 * 4;
            int rowb = bi + rl0;
            float4 rs4 = *(const float4*)&rowsig[rowb];
            int4   tg4 = *(const int4*)&target[rowb];
            #pragma unroll
            for (int nf = 0; nf < 4; ++nf) {
                int cl = wn * 64 + nf * 16 + ml;
                int col = bj + cl;
                float sc = rnorm[col];
                int cls = col >> 3;
                int clsl = cl >> 3;
                #pragma unroll
                for (int i = 0; i < 4; ++i) {
                    int rl = rl0 + i;
                    float v = acc[mf][nf][i] * sc;
                    float sg = ((const float*)&rs4)[i] * (1.0f / 22.616f);
                    float hiT = 1.80f * sg, loT = 1.47f * sg;
                    int tg = ((const int*)&tg4)[i];
                    if (cls == tg) {
                        atomicAdd(&e_cls[rl * 32 + clsl], v);
                    } else if (v >= hiT) {
                        atomicAdd(&e_cls[rl * 32 + clsl], v);
                        atomicAdd(&e_nd[rl], 1u);
                    } else if (v >= loT) {
                        unsigned u = atomicAdd(&e_cnt[rl], 1u);
                        if (u < BAND_CAP_BLK) {
                            e_bv[rl * BAND_CAP_BLK + u] = v;
                            e_bc[rl * BAND_CAP_BLK + u] = (ushort_t)col;
                        }
                    }
                }
            }
        }
        __syncthreads();

        int bjc = bj >> 3;
        #pragma unroll
        for (int i = t; i < 8192; i += 512) {
            int rl = i >> 5, c = i & 31;
            g_cls[(size_t)(bi + rl) * C_CLS + bjc + c] = e_cls[i];
        }
        if (t < 256) {
            int row = bi + t;
            unsigned cbb = e_cnt[t];
            unsigned nd = e_nd[t];
            if (nd) atomicAdd(&g_ndef[row], nd);
            if (cbb) {
                unsigned cc = (cbb > BAND_CAP_BLK) ? BAND_CAP_BLK : cbb;
                unsigned base = atomicAdd(&g_cnt[row], cc);
                if (cbb > BAND_CAP_BLK || base + cc > ROW_CAP) g_flag[row] = 1u;
                for (unsigned j = 0; j < cc; ++j) {
                    if (base + j >= ROW_CAP) break;
                    g_bval[(size_t)row * ROW_CAP + base + j] = e_bv[t * BAND_CAP_BLK + j];
                    g_bcol[(size_t)row * ROW_CAP + base + j] = e_bc[t * BAND_CAP_BLK + j];
                }
            }
        }
    } else {
        // ================= gemm1: Pbf(8192x512) @ Stbf(1024x512)^T ===========
        int id = bx - 256;               // 0..255
        int bi = (id >> 3) * 256, bj = (id & 7) * 128;
        int wm = w >> 1, wn = w & 1;     // 4M x 2N, per-wave 64x64
        ushort_t* sA0 = smem;            // [256][64]
        ushort_t* sB0 = smem + 16384;    // [128][64]
        ushort_t* sA1 = smem + 32768;
        ushort_t* sB1 = smem + 49152;

        floatx4 acc[4][4];
        #pragma unroll
        for (int mf = 0; mf < 4; ++mf)
            #pragma unroll
            for (int nf = 0; nf < 4; ++nf)
                acc[mf][nf] = (floatx4){0.f, 0.f, 0.f, 0.f};

        #define STAGE1(sa, sb, k0) do {                                        \
            _Pragma("unroll")                                                  \
            for (int it = 0; it < 4; ++it) {                                   \
                int c = w * 256 + it * 64 + lane;                              \
                int m = c >> 3, s = c & 7, qq = s ^ (m & 7);                   \
                ld_g2l_16(Pbf + ((size_t)(bi + m) << 9) + (k0) + qq * 8,       \
                          &(sa)[c * 8]);                                       \
            }                                                                  \
            _Pragma("unroll")                                                  \
            for (int it = 0; it < 2; ++it) {                                   \
                int c = w * 128 + it * 64 + lane;                              \
                int m = c >> 3, s = c & 7, qq = s ^ (m & 7);                   \
                ld_g2l_16(Stbf + ((size_t)(bj + m) << 9) + (k0) + qq * 8,      \
                          &(sb)[c * 8]);                                       \
            }                                                                  \
        } while (0)

        STAGE1(sA0, sB0, 0);
        __syncthreads();
        #pragma unroll
        for (int tt = 0; tt < 8; ++tt) {
            ushort_t* cA = (tt & 1) ? sA1 : sA0;
            ushort_t* cB = (tt & 1) ? sB1 : sB0;
            if (tt < 7) {
                if (tt & 1) STAGE1(sA0, sB0, (tt + 1) * 64);
                else        STAGE1(sA1, sB1, (tt + 1) * 64);
            }
            #pragma unroll
            for (int kk = 0; kk < 2; ++kk) {
                bf16x8 bfr[4];
                #pragma unroll
                for (int nf = 0; nf < 4; ++nf) {
                    int n = wn * 64 + nf * 16 + ml;
                    int s = (kk * 4 + q4) ^ (n & 7);
                    bfr[nf] = *(const bf16x8*)&cB[n * 64 + s * 8];
                }
                #pragma unroll
                for (int mf = 0; mf < 4; ++mf) {
                    int m = wm * 64 + mf * 16 + ml;
                    int s = (kk * 4 + q4) ^ (m & 7);
                    bf16x8 af = *(const bf16x8*)&cA[m * 64 + s * 8];
                    #pragma unroll
                    for (int nf = 0; nf < 4; ++nf)
                        acc[mf][nf] = __builtin_amdgcn_mfma_f32_16x16x32_bf16(
                            af, bfr[nf], acc[mf][nf], 0, 0, 0);
                }
            }
            __syncthreads();
        }
        #undef STAGE1

        // ---- fused per-row-chunk logsumexp partials (no logits write) -------
        int cj = bj >> 7;                // col-chunk 0..7
        float mloc[4][4], sloc[4][4];
        #pragma unroll
        for (int mf = 0; mf < 4; ++mf) {
            int rowb = bi + wm * 64 + mf * 16 + q4 * 4;
            float4 rnr = *(const float4*)&rnorm[rowb];
            #pragma unroll
            for (int i = 0; i < 4; ++i) {
                float mm = -1e30f;
                #pragma unroll
                for (int nf = 0; nf < 4; ++nf)
                    mm = fmaxf(mm, acc[mf][nf][i] * ((const float*)&rnr)[i]);
                mloc[mf][i] = mm;
            }
        }
        #pragma unroll
        for (int off = 1; off < 16; off <<= 1)
            #pragma unroll
            for (int mf = 0; mf < 4; ++mf)
                #pragma unroll
                for (int i = 0; i < 4; ++i)
                    mloc[mf][i] = fmaxf(mloc[mf][i], __shfl_xor(mloc[mf][i], off));
        #pragma unroll
        for (int mf = 0; mf < 4; ++mf) {
            int rowb = bi + wm * 64 + mf * 16 + q4 * 4;
            float4 rnr = *(const float4*)&rnorm[rowb];
            #pragma unroll
            for (int i = 0; i < 4; ++i) {
                float ss = 0.f;
                int row = rowb + i;
                #pragma unroll
                for (int nf = 0; nf < 4; ++nf) {
                    float v = acc[mf][nf][i] * ((const float*)&rnr)[i];
                    ss += expf(v - mloc[mf][i]);
                    int col = bj + wn * 64 + nf * 16 + ml;
                    if (col == (row >> 3)) g_diag[row] = v;
                }
                sloc[mf][i] = ss;
            }
        }
        #pragma unroll
        for (int off = 1; off < 16; off <<= 1)
            #pragma unroll
            for (int mf = 0; mf < 4; ++mf)
                #pragma unroll
                for (int i = 0; i < 4; ++i)
                    sloc[mf][i] += __shfl_xor(sloc[mf][i], off);
        float* s_m = (float*)smem;          // [256][2]
        float* s_s = s_m + 512;             // [256][2]
        if (ml == 0) {
            #pragma unroll
            for (int mf = 0; mf < 4; ++mf)
                #pragma unroll
                for (int i = 0; i < 4; ++i) {
                    int r = wm * 64 + mf * 16 + q4 * 4 + i;
                    s_m[r * 2 + wn] = mloc[mf][i];
                    s_s[r * 2 + wn] = sloc[mf][i];
                }
        }
        __syncthreads();
        if (t < 256) {
            float m0 = s_m[2 * t], m1 = s_m[2 * t + 1];
            float s0 = s_s[2 * t], s1 = s_s[2 * t + 1];
            float M = fmaxf(m0, m1);
            float S = s0 * expf(m0 - M) + s1 * expf(m1 - M);
            g_mx[(size_t)(bi + t) * 8 + cj] = M;
            g_se[(size_t)(bi + t) * 8 + cj] = S;
        }
    }
}

// ---- K3 (r10-verbatim): finish-rowloss (2048) + regloss-combine (128) -------
__device__ inline void suffix_select1(unsigned* s_hist, unsigned kk,
                                      unsigned* s_wtot, unsigned* sh_bin,
                                      unsigned* sh_k, int t, int lane, int wid) {
    unsigned h = s_hist[t];
    unsigned v = h;
    #pragma unroll
    for (int off = 1; off < 64; off <<= 1) {
        unsigned o = __shfl_down(v, off);
        if (lane + off < 64) v += o;
    }
    if (lane == 0) s_wtot[wid] = v;
    __syncthreads();
    unsigned above = v - h;
    for (int w2 = wid + 1; w2 < 4; ++w2) above += s_wtot[w2];
    unsigned cum = above + h;
    if (cum >= kk && above < kk) { *sh_bin = (unsigned)t; *sh_k = kk - above; }
    __syncthreads();
}

__global__ __launch_bounds__(256) void k_finish(const int* __restrict__ target,
                                                const float* __restrict__ rowsig,
                                                const float* __restrict__ rnorm,
                                                const ushort_t* __restrict__ Abf,
                                                const ushort_t* __restrict__ Pbf,
                                                const float* __restrict__ g_cls,
                                                const float* __restrict__ g_bval,
                                                const ushort_t* __restrict__ g_bcol,
                                                const unsigned* __restrict__ g_cnt,
                                                const unsigned* __restrict__ g_ndef,
                                                const unsigned* __restrict__ g_flag,
                                                float* __restrict__ loss_part,
                                                const float* __restrict__ g_mx,
                                                const float* __restrict__ g_se,
                                                const float* __restrict__ g_diag,
                                                float* __restrict__ reg_part) {
    __shared__ __align__(16) unsigned char smem[16384];     // 16 KB union
    int bx = blockIdx.x, t = threadIdx.x;
    int lane = t & 63, wid = t >> 6;

    if (bx < 2048) {
        // ================= finish-rowloss: select band elems, softmax, loss ==
        float*    s_cls  = (float*)smem;                    // 1024 f
        float*    s_bval = (float*)(smem + 4096);           // 512 f
        ushort_t* s_bcol = (ushort_t*)(smem + 6144);        // 512 u16
        unsigned* s_hist = (unsigned*)(smem + 7168);        // 256 u32
        float*    s_arow = (float*)(smem + 8192);           // 512 f (fallback only)
        unsigned* s_wtot = (unsigned*)(smem + 10240);       // 4
        unsigned* shv    = (unsigned*)(smem + 10256);       // gc, bin, k
        float*    shf    = (float*)(smem + 10272);          // thr
        float*    red    = (float*)(smem + 10288);          // 4
        float*    s_gval = (float*)(smem + 10304);          // 64 f

        int b = bx;
        int tgt = target[b];
        float sig = rowsig[b] * (1.0f / 22.616f);
        float hiT = 1.80f * sig, loT = 1.47f * sig;
        float binscale = 256.0f / (hiT - loT);

        ((float4*)s_cls)[t] = ((const float4*)(g_cls + (size_t)b * C_CLS))[t];
        unsigned cnt = g_cnt[b], nd = g_ndef[b], fl = g_flag[b];
        int kq = (TOPK - NPROXY) - (int)nd;
        int ok = (fl == 0u) && (cnt <= ROW_CAP) && (kq >= 0) && ((int)cnt >= kq);
        if (t == 0) shv[0] = 0u;
        s_hist[t] = 0u;
        __syncthreads();

        if (ok) {
            if (kq > 0) {
                for (int j = t; j < (int)cnt; j += 256) {
                    float v = g_bval[(size_t)b * ROW_CAP + j];
                    s_bval[j] = v;
                    s_bcol[j] = g_bcol[(size_t)b * ROW_CAP + j];
                    int bin = (int)((v - loT) * binscale);
                    bin = (bin > 255) ? 255 : bin;
                    atomicAdd(&s_hist[bin], 1u);
                }
                __syncthreads();
                suffix_select1(s_hist, (unsigned)kq, s_wtot, &shv[1], &shv[2], t, lane, wid);
                int Bb = (int)shv[1];
                int knew = (int)shv[2];
                for (int j = t; j < (int)cnt; j += 256) {
                    float v = s_bval[j];
                    int bin = (int)((v - loT) * binscale);
                    bin = (bin > 255) ? 255 : bin;
                    if (bin == Bb) {
                        unsigned g = atomicAdd(&shv[0], 1u);
                        if (g < GCAP) s_gval[g] = v;
                    }
                }
                __syncthreads();
                int gc = (int)shv[0];
                if (gc <= GCAP) {
                    if (t < gc) {
                        float vj = s_gval[t];
                        unsigned g = 0, geq = 0;
                        for (int i = 0; i < gc; ++i) {
                            float vi = s_gval[i];
                            g   += (vi > vj) ? 1u : 0u;
                            geq += (vi >= vj) ? 1u : 0u;
                        }
                        if (g < (unsigned)knew && geq >= (unsigned)knew) shf[0] = vj;
                    }
                } else {
                    for (int j = t; j < (int)cnt; j += 256) {
                        float vj = s_bval[j];
                        unsigned g = 0, geq = 0;
                        for (int i = 0; i < (int)cnt; ++i) {
                            float vi = s_bval[i];
                            g   += (vi > vj) ? 1u : 0u;
                            geq += (vi >= vj) ? 1u : 0u;
                        }
                        if (g < (unsigned)kq && geq >= (unsigned)kq) shf[0] = vj;
                    }
                }
                __syncthreads();
                float thr = shf[0];
                for (int j = t; j < (int)cnt; j += 256)
                    if (s_bval[j] >= thr)
                        atomicAdd(&s_cls[s_bcol[j] >> 3], s_bval[j]);
            }
        } else {
            // exact fallback: recompute full sim row (never taken for this input)
            for (int i = t; i < DIM; i += 256)
                s_arow[i] = bf2f(Abf[(size_t)b * DIM + i]);
            #pragma unroll
            for (int i = 0; i < 4; ++i) s_cls[t + 256 * i] = 0.f;
            __syncthreads();
            float4 v4[8];
            for (int p = 0; p < 8; ++p) {
                int f = t + 256 * p;
                float vv[4];
                for (int e = 0; e < 4; ++e) {
                    int col = 4 * f + e;
                    const ushort_t* pc = Pbf + (size_t)col * DIM;
                    float a = 0.f;
                    for (int d = 0; d < DIM; ++d)
                        a += s_arow[d] * bf2f(pc[d]);
                    vv[e] = a * rnorm[col];
                }
                float4 o; o.x = vv[0]; o.y = vv[1]; o.z = vv[2]; o.w = vv[3];
                v4[p] = o;
            }
            #pragma unroll
            for (int p = 0; p < 8; ++p) {
                int f = t + 256 * p;
                const float* pv = (const float*)&v4[p];
                if ((f >> 1) == tgt)
                    atomicAdd(&s_cls[tgt], pv[0] + pv[1] + pv[2] + pv[3]);
            }
            unsigned L = 0u, R = 0xFFFFFFFFu;
            for (int it = 0; it < 33 && R - L > 1; ++it) {
                unsigned mid = L + ((R - L) >> 1);
                float c = 0.f;
                #pragma unroll
                for (int p = 0; p < 8; ++p) {
                    int f = t + 256 * p;
                    const float* pv = (const float*)&v4[p];
                    if ((f >> 1) != tgt) {
                        #pragma unroll
                        for (int e = 0; e < 4; ++e)
                            c += (f2ord(pv[e]) >= mid) ? 1.f : 0.f;
                    }
                }
                c = block_reduce(c, 0, red, t);
                if (c >= (float)(TOPK - NPROXY)) L = mid; else R = mid;
                __syncthreads();
            }
            #pragma unroll
            for (int p = 0; p < 8; ++p) {
                int f = t + 256 * p;
                const float* pv = (const float*)&v4[p];
                if ((f >> 1) != tgt) {
                    #pragma unroll
                    for (int e = 0; e < 4; ++e)
                        if (f2ord(pv[e]) >= L)
                            atomicAdd(&s_cls[f >> 1], pv[e]);
                }
            }
        }
        __syncthreads();

        float4 cv = ((const float4*)s_cls)[t];
        float m = -1e30f;
        if (cv.x != 0.0f) m = fmaxf(m, cv.x);
        if (cv.y != 0.0f) m = fmaxf(m, cv.y);
        if (cv.z != 0.0f) m = fmaxf(m, cv.z);
        if (cv.w != 0.0f) m = fmaxf(m, cv.w);
        m = block_reduce(m, 1, red, t);
        float se = 0.f;
        if (cv.x != 0.0f) se += expf(cv.x - m);
        if (cv.y != 0.0f) se += expf(cv.y - m);
        if (cv.z != 0.0f) se += expf(cv.z - m);
        if (cv.w != 0.0f) se += expf(cv.w - m);
        se = block_reduce(se, 0, red, t);
        if (t == 0) {
            float lt = s_cls[tgt];
            float predict_t = expf(lt - m) / (1e-8f * expf(-m) + se);
            loss_part[b] = -logf(predict_t + 1e-20f);
        }
    } else {
        // ================= regloss combine: 128 blocks x 64 rows =============
        float* red2 = (float*)smem;
        int rb = bx - 2048;
        float val = 0.f;
        if (t < 64) {
            int row = rb * 64 + t;
            float mj[8], sj[8];
            float M = -1e30f;
            #pragma unroll
            for (int j = 0; j < 8; ++j) {
                mj[j] = g_mx[(size_t)row * 8 + j];
                sj[j] = g_se[(size_t)row * 8 + j];
                M = fmaxf(M, mj[j]);
            }
            float S = 0.f;
            #pragma unroll
            for (int j = 0; j < 8; ++j) S += sj[j] * expf(mj[j] - M);
            val = M + logf(S) - g_diag[row];
        }
        val = block_reduce(val, 0, red2, t);
        if (t == 0) reg_part[rb] = val;
    }
}

// ---------------- K4: finalize (reduce 2048 + 128 partials) ------------------
__global__ __launch_bounds__(256) void k_final(const float* __restrict__ lp,
                                               const float* __restrict__ rp,
                                               float* __restrict__ out) {
    __shared__ float red[4];
    int t = threadIdx.x;
    float4 a = ((const float4*)lp)[t];
    float4 b = ((const float4*)lp)[t + 256];
    float ls = a.x + a.y + a.z + a.w + b.x + b.y + b.z + b.w;
    float rs = 0.f;
    if (t < 32) {
        float4 c = ((const float4*)rp)[t];
        rs = c.x + c.y + c.z + c.w;
    }
    ls = block_reduce(ls, 0, red, t);
    rs = block_reduce(rs, 0, red, t);
    if (t == 0) {
        float lc = ls / (float)BATCH;
        float rg = rs / (float)ALLNUM;
        out[0] = lc + LAM * rg;
        out[1] = lc;
    }
}

extern "C" void kernel_launch(void* const* d_in, const int* in_sizes, int n_in,
                              void* d_out, int out_size, void* d_ws, size_t ws_size,
                              hipStream_t stream) {
    const float* input  = (const float*)d_in[0];
    const int*   target = (const int*)d_in[1];
    const float* P      = (const float*)d_in[2];

    float* ws        = (float*)d_ws;
    float* rnorm     = ws + WS_RNORM;
    float* rowsig    = ws + WS_SIG;
    float* loss_part = ws + WS_LP;
    float* reg_part  = ws + WS_RP;
    unsigned* g_cnt  = (unsigned*)(ws + WS_CNT);
    unsigned* g_ndef = (unsigned*)(ws + WS_NDEF);
    unsigned* g_flag = (unsigned*)(ws + WS_FLAG);
    float* g_cls     = ws + WS_CLS;
    float* g_bval    = ws + WS_BVAL;
    ushort_t* g_bcol = (ushort_t*)(ws + WS_BCOL);
    ushort_t* Abf    = (ushort_t*)(ws + WS_ABF);
    ushort_t* Pbf    = (ushort_t*)(ws + WS_PBF);
    ushort_t* Stbf   = (ushort_t*)(ws + WS_STBF);
    float* g_mx      = ws + WS_MX;
    float* g_se      = ws + WS_SE;
    float* g_diag    = ws + WS_DIAG;
    float* out       = (float*)d_out;

    hipLaunchKernelGGL(k_prep1, dim3(64 + 1024 + 1024 + 1), dim3(256), 0, stream,
                       P, input, rnorm, rowsig, Abf, Pbf, Stbf, g_cnt);
    hipLaunchKernelGGL(k_gemms, dim3(512), dim3(512), 0, stream,
                       Abf, Pbf, Stbf, rnorm, rowsig, target,
                       g_cls, g_bval, g_bcol, g_cnt, g_ndef, g_flag,
                       g_mx, g_se, g_diag);
    hipLaunchKernelGGL(k_finish, dim3(2048 + 128), dim3(256), 0, stream,
                       target, rowsig, rnorm, Abf, Pbf,
                       g_cls, g_bval, g_bcol, g_cnt, g_ndef, g_flag,
                       loss_part, g_mx, g_se, g_diag, reg_part);
    hipLaunchKernelGGL(k_final, dim3(1), dim3(256), 0, stream,
                       loss_part, reg_part, out);
}

// Round 12
// 148.038 us; speedup vs baseline: 1.0348x; 1.0348x over previous
//
#include <hip/hip_runtime.h>
#include <hip/hip_bf16.h>
#include <math.h>

#define C_CLS   1024
#define NPROXY  8
#define ALLNUM  8192
#define DIM     512
#define TOPK    410
#define LAM     0.3f
#define BATCH   2048

#define BAND_CAP_BLK 40     // per-row per-256-col-tile band capacity (mean ~9, +10 sigma)
#define ROW_CAP      512    // per-row total band capacity (mean ~287)
#define GCAP         64

typedef __bf16 bf16x8 __attribute__((ext_vector_type(8)));
typedef float floatx4 __attribute__((ext_vector_type(4)));
typedef unsigned short ushort_t;

// ws layout (float offsets)
#define WS_RNORM 0                       // 8192
#define WS_SIG   8192                    // 2048
#define WS_LP    10240                   // 2048
#define WS_RP    12288                   // 2048 (reg_part uses 128)
#define WS_CNT   14336                   // 2048 u32 (band count per row)
#define WS_NDEF  16384                   // 2048 u32 (definite count per row)
#define WS_FLAG  18432                   // 2048 u32 (overflow -> fallback)
#define WS_CLS   20480                   // 2048*1024 f32 class sums (definite+tgt)
#define WS_BVAL  (WS_CLS + 2048*1024)    // 2048*512 f32 band values
#define WS_BCOL  (WS_BVAL + 2048*512)    // 2048*512 u16 band cols
#define WS_ABF   (WS_BCOL + 2048*256)    // 2048*512 bf16
#define WS_PBF   (WS_ABF + 524288)       // 8192*512 bf16
#define WS_STBF  (WS_PBF + 2097152)      // 1024*512 bf16
#define WS_MX    (WS_STBF + 262144)      // 8192*8 f32 lse partial max
#define WS_SE    (WS_MX + 65536)         // 8192*8 f32 lse partial sumexp
#define WS_DIAG  (WS_SE + 65536)         // 8192 f32 diag logits

// ---------------- helpers ----------------------------------------------------
__device__ inline float block_reduce(float v, int is_max, float* red, int t) {
    #pragma unroll
    for (int o = 32; o > 0; o >>= 1) {
        float w = __shfl_down(v, o);
        v = is_max ? fmaxf(v, w) : (v + w);
    }
    __syncthreads();
    if ((t & 63) == 0) red[t >> 6] = v;
    __syncthreads();
    float r = is_max ? fmaxf(fmaxf(red[0], red[1]), fmaxf(red[2], red[3]))
                     : (red[0] + red[1] + red[2] + red[3]);
    __syncthreads();
    return r;
}

__device__ inline ushort_t f2bf(float f) {   // RNE float->bf16
    unsigned u = __float_as_uint(f);
    return (ushort_t)((u + 0x7FFFu + ((u >> 16) & 1u)) >> 16);
}

__device__ inline float bf2f(ushort_t u) {
    return __uint_as_float(((unsigned)u) << 16);
}

__device__ inline void ld_g2l_16(const void* g, void* l) {
    __builtin_amdgcn_global_load_lds(
        (const __attribute__((address_space(1))) unsigned int*)g,
        (__attribute__((address_space(3))) unsigned int*)l,
        16, 0, 0);
}

__device__ inline unsigned f2ord(float f) {  // monotone float->uint
    unsigned u = __float_as_uint(f);
    return (u & 0x80000000u) ? ~u : (u | 0x80000000u);
}

// ---- K1 (r2-verbatim): colnorm+buildSt(256) | convA(1024) | tconvP(4096) | zero(1)
__global__ __launch_bounds__(256) void k_prep1(const float* __restrict__ P,
                                               const float* __restrict__ input,
                                               float* __restrict__ rnorm,
                                               float* __restrict__ rowsig,
                                               ushort_t* __restrict__ Abf,
                                               ushort_t* __restrict__ Pbf,
                                               ushort_t* __restrict__ Stbf,
                                               unsigned* __restrict__ zaux) {
    __shared__ float tile[32][33];
    __shared__ float s_rn[32];
    float* cred = &tile[0][0];
    int bx = blockIdx.x, t = threadIdx.x;
    if (bx < 256) {
        // colnorm: 32 cols/block (= 4 classes), 8 d-groups of 64
        int tc = t & 31, g = t >> 5;
        int c = bx * 32 + tc;
        const float* pc = P + (size_t)(g * 64) * ALLNUM + c;
        float s = 0.f;
        #pragma unroll 8
        for (int d = 0; d < 64; ++d) {
            float v = pc[(size_t)d * ALLNUM];
            s += v * v;
        }
        cred[g * 32 + tc] = s;
        __syncthreads();
        if (g == 0) {
            float tot = 0.f;
            #pragma unroll
            for (int k = 0; k < 8; ++k) tot += cred[k * 32 + tc];
            float r = 1.0f / fmaxf(sqrtf(tot), 1e-12f);
            rnorm[c] = r;
            s_rn[tc] = r;
        }
        __syncthreads();
        // fused buildSt: St[cls][d] = sum_n P[d][cls*8+n]*rnorm  (4 classes here)
        #pragma unroll
        for (int p = 0; p < 8; ++p) {
            int idx = t + 256 * p;          // 0..2047
            int d = idx >> 2, cc = idx & 3;
            const float* pp = P + (size_t)d * ALLNUM + bx * 32 + cc * 8;
            const float* rr = &s_rn[cc * 8];
            float4 a = *(const float4*)pp;
            float4 b = *(const float4*)(pp + 4);
            float v = a.x * rr[0] + a.y * rr[1] + a.z * rr[2] + a.w * rr[3] +
                      b.x * rr[4] + b.y * rr[5] + b.z * rr[6] + b.w * rr[7];
            Stbf[(size_t)(bx * 4 + cc) * DIM + d] = f2bf(v);
        }
    } else if (bx < 256 + 1024) {
        // convA: input fp32 -> bf16 + row norms (block = exactly 2 rows)
        int a = bx - 256;
        int idx = a * 256 + t;
        float4 v = ((const float4*)input)[idx];
        ushort4 o;
        o.x = f2bf(v.x); o.y = f2bf(v.y); o.z = f2bf(v.z); o.w = f2bf(v.w);
        ((ushort4*)Abf)[idx] = o;
        float sq = v.x * v.x + v.y * v.y + v.z * v.z + v.w * v.w;
        #pragma unroll
        for (int off = 32; off > 0; off >>= 1) sq += __shfl_down(sq, off);
        int lane = t & 63, w = t >> 6;
        if (lane == 0) cred[w] = sq;
        __syncthreads();
        if (t == 0) {
            rowsig[2 * a]     = sqrtf(cred[0] + cred[1]);
            rowsig[2 * a + 1] = sqrtf(cred[2] + cred[3]);
        }
    } else if (bx < 256 + 1024 + 4096) {
        // tconv: P [512][8192] fp32 -> Pbf [8192][512] bf16
        int id = bx - 1280;
        int c0 = (id & 255) * 32, r0 = (id >> 8) * 32;
        int tc = t & 31, tr = t >> 5;
        #pragma unroll
        for (int p = 0; p < 4; ++p)
            tile[tr + p * 8][tc] = P[(size_t)(r0 + tr + p * 8) * ALLNUM + c0 + tc];
        __syncthreads();
        #pragma unroll
        for (int p = 0; p < 4; ++p) {
            int oc = tr + p * 8;
            Pbf[(size_t)(c0 + oc) * DIM + r0 + tc] = f2bf(tile[tc][oc]);
        }
    } else {
        // zero cnt/ndef/flag (contiguous 3*2048 u32)
        for (int i = t; i < 3 * 2048; i += 256) zaux[i] = 0u;
    }
}

// ---- K2: r2-verbatim 2-phase dbuf gemms (direct mapping, no remap) ----------
//      gemm0 (bx 0..255):  256x256 sim tiles + binning epilogue
//      gemm1 (bx 256..511): 256x128 tiles, fused LSE partials epilogue
__global__ __launch_bounds__(512, 2) void k_gemms(const ushort_t* __restrict__ Abf,
                                                  const ushort_t* __restrict__ Pbf,
                                                  const ushort_t* __restrict__ Stbf,
                                                  const float* __restrict__ rnorm,
                                                  const float* __restrict__ rowsig,
                                                  const int* __restrict__ target,
                                                  float* __restrict__ g_cls,
                                                  float* __restrict__ g_bval,
                                                  ushort_t* __restrict__ g_bcol,
                                                  unsigned* __restrict__ g_cnt,
                                                  unsigned* __restrict__ g_ndef,
                                                  unsigned* __restrict__ g_flag,
                                                  float* __restrict__ g_mx,
                                                  float* __restrict__ g_se,
                                                  float* __restrict__ g_diag) {
    __shared__ __align__(16) ushort_t smem[65536];   // 128 KB: dbuf A+B
    int bx = blockIdx.x, t = threadIdx.x;
    int w = t >> 6, lane = t & 63;
    int ml = lane & 15, q4 = lane >> 4;

    if (bx < 256) {
        // ================= gemm0: sim = Abf(2048x512) @ Pbf(8192x512)^T ======
        int bi = (bx >> 5) * 256, bj = (bx & 31) * 256;
        int wm = w >> 2, wn = w & 3;     // 2M x 4N, per-wave 128x64
        ushort_t* sA0 = smem;            // [256][64]
        ushort_t* sB0 = smem + 16384;
        ushort_t* sA1 = smem + 32768;
        ushort_t* sB1 = smem + 49152;

        floatx4 acc[8][4];
        #pragma unroll
        for (int mf = 0; mf < 8; ++mf)
            #pragma unroll
            for (int nf = 0; nf < 4; ++nf)
                acc[mf][nf] = (floatx4){0.f, 0.f, 0.f, 0.f};

        #define STAGE0(sa, sb, k0) do {                                        \
            _Pragma("unroll")                                                  \
            for (int it = 0; it < 4; ++it) {                                   \
                int c = w * 256 + it * 64 + lane;                              \
                int m = c >> 3, s = c & 7, qq = s ^ (m & 7);                   \
                ld_g2l_16(Abf + ((size_t)(bi + m) << 9) + (k0) + qq * 8,       \
                          &(sa)[c * 8]);                                       \
            }                                                                  \
            _Pragma("unroll")                                                  \
            for (int it = 0; it < 4; ++it) {                                   \
                int c = w * 256 + it * 64 + lane;                              \
                int m = c >> 3, s = c & 7, qq = s ^ (m & 7);                   \
                ld_g2l_16(Pbf + ((size_t)(bj + m) << 9) + (k0) + qq * 8,       \
                          &(sb)[c * 8]);                                       \
            }                                                                  \
        } while (0)

        STAGE0(sA0, sB0, 0);
        __syncthreads();
        #pragma unroll
        for (int tt = 0; tt < 8; ++tt) {
            ushort_t* cA = (tt & 1) ? sA1 : sA0;
            ushort_t* cB = (tt & 1) ? sB1 : sB0;
            if (tt < 7) {
                if (tt & 1) STAGE0(sA0, sB0, (tt + 1) * 64);
                else        STAGE0(sA1, sB1, (tt + 1) * 64);
            }
            #pragma unroll
            for (int kk = 0; kk < 2; ++kk) {
                bf16x8 bfr[4];
                #pragma unroll
                for (int nf = 0; nf < 4; ++nf) {
                    int n = wn * 64 + nf * 16 + ml;
                    int s = (kk * 4 + q4) ^ (n & 7);
                    bfr[nf] = *(const bf16x8*)&cB[n * 64 + s * 8];
                }
                #pragma unroll
                for (int mf = 0; mf < 8; ++mf) {
                    int m = wm * 128 + mf * 16 + ml;
                    int s = (kk * 4 + q4) ^ (m & 7);
                    bf16x8 af = *(const bf16x8*)&cA[m * 64 + s * 8];
                    #pragma unroll
                    for (int nf = 0; nf < 4; ++nf)
                        acc[mf][nf] = __builtin_amdgcn_mfma_f32_16x16x32_bf16(
                            af, bfr[nf], acc[mf][nf], 0, 0, 0);
                }
            }
            __syncthreads();
        }
        #undef STAGE0

        // ---- fused binning epilogue (LDS aliased over staging buffers) ------
        unsigned char* sb8 = (unsigned char*)smem;
        float*    e_cls = (float*)sb8;                  // [256][32] f32 (32768 B)
        float*    e_bv  = (float*)(sb8 + 32768);        // [256][40] f32 (40960 B)
        ushort_t* e_bc  = (ushort_t*)(sb8 + 73728);     // [256][40] u16 (20480 B)
        unsigned* e_cnt = (unsigned*)(sb8 + 94208);     // [256] u32
        unsigned* e_nd  = (unsigned*)(sb8 + 95232);     // [256] u32

        #pragma unroll
        for (int i = t; i < 8192; i += 512) e_cls[i] = 0.f;
        if (t < 256) { e_cnt[t] = 0u; e_nd[t] = 0u; }
        __syncthreads();

        #pragma unroll
        for (int mf = 0; mf < 8; ++mf) {
            int rl0 = wm * 128 + mf * 16 + q4 * 4;
            int rowb = bi + rl0;
            float4 rs4 = *(const float4*)&rowsig[rowb];
            int4   tg4 = *(const int4*)&target[rowb];
            #pragma unroll
            for (int nf = 0; nf < 4; ++nf) {
                int cl = wn * 64 + nf * 16 + ml;
                int col = bj + cl;
                float sc = rnorm[col];
                int cls = col >> 3;
                int clsl = cl >> 3;
                #pragma unroll
                for (int i = 0; i < 4; ++i) {
                    int rl = rl0 + i;
                    float v = acc[mf][nf][i] * sc;
                    float sg = ((const float*)&rs4)[i] * (1.0f / 22.616f);
                    float hiT = 1.80f * sg, loT = 1.47f * sg;
                    int tg = ((const int*)&tg4)[i];
                    if (cls == tg) {
                        atomicAdd(&e_cls[rl * 32 + clsl], v);
                    } else if (v >= hiT) {
                        atomicAdd(&e_cls[rl * 32 + clsl], v);
                        atomicAdd(&e_nd[rl], 1u);
                    } else if (v >= loT) {
                        unsigned u = atomicAdd(&e_cnt[rl], 1u);
                        if (u < BAND_CAP_BLK) {
                            e_bv[rl * BAND_CAP_BLK + u] = v;
                            e_bc[rl * BAND_CAP_BLK + u] = (ushort_t)col;
                        }
                    }
                }
            }
        }
        __syncthreads();

        int bjc = bj >> 3;
        #pragma unroll
        for (int i = t; i < 8192; i += 512) {
            int rl = i >> 5, c = i & 31;
            g_cls[(size_t)(bi + rl) * C_CLS + bjc + c] = e_cls[i];
        }
        if (t < 256) {
            int row = bi + t;
            unsigned cbb = e_cnt[t];
            unsigned nd = e_nd[t];
            if (nd) atomicAdd(&g_ndef[row], nd);
            if (cbb) {
                unsigned cc = (cbb > BAND_CAP_BLK) ? BAND_CAP_BLK : cbb;
                unsigned base = atomicAdd(&g_cnt[row], cc);
                if (cbb > BAND_CAP_BLK || base + cc > ROW_CAP) g_flag[row] = 1u;
                for (unsigned j = 0; j < cc; ++j) {
                    if (base + j >= ROW_CAP) break;
                    g_bval[(size_t)row * ROW_CAP + base + j] = e_bv[t * BAND_CAP_BLK + j];
                    g_bcol[(size_t)row * ROW_CAP + base + j] = e_bc[t * BAND_CAP_BLK + j];
                }
            }
        }
    } else {
        // ================= gemm1: Pbf(8192x512) @ Stbf(1024x512)^T ===========
        int id = bx - 256;               // 0..255
        int bi = (id >> 3) * 256, bj = (id & 7) * 128;
        int wm = w >> 1, wn = w & 1;     // 4M x 2N, per-wave 64x64
        ushort_t* sA0 = smem;            // [256][64]
        ushort_t* sB0 = smem + 16384;    // [128][64]
        ushort_t* sA1 = smem + 32768;
        ushort_t* sB1 = smem + 49152;

        floatx4 acc[4][4];
        #pragma unroll
        for (int mf = 0; mf < 4; ++mf)
            #pragma unroll
            for (int nf = 0; nf < 4; ++nf)
                acc[mf][nf] = (floatx4){0.f, 0.f, 0.f, 0.f};

        #define STAGE1(sa, sb, k0) do {                                        \
            _Pragma("unroll")                                                  \
            for (int it = 0; it < 4; ++it) {                                   \
                int c = w * 256 + it * 64 + lane;                              \
                int m = c >> 3, s = c & 7, qq = s ^ (m & 7);                   \
                ld_g2l_16(Pbf + ((size_t)(bi + m) << 9) + (k0) + qq * 8,       \
                          &(sa)[c * 8]);                                       \
            }                                                                  \
            _Pragma("unroll")                                                  \
            for (int it = 0; it < 2; ++it) {                                   \
                int c = w * 128 + it * 64 + lane;                              \
                int m = c >> 3, s = c & 7, qq = s ^ (m & 7);                   \
                ld_g2l_16(Stbf + ((size_t)(bj + m) << 9) + (k0) + qq * 8,      \
                          &(sb)[c * 8]);                                       \
            }                                                                  \
        } while (0)

        STAGE1(sA0, sB0, 0);
        __syncthreads();
        #pragma unroll
        for (int tt = 0; tt < 8; ++tt) {
            ushort_t* cA = (tt & 1) ? sA1 : sA0;
            ushort_t* cB = (tt & 1) ? sB1 : sB0;
            if (tt < 7) {
                if (tt & 1) STAGE1(sA0, sB0, (tt + 1) * 64);
                else        STAGE1(sA1, sB1, (tt + 1) * 64);
            }
            #pragma unroll
            for (int kk = 0; kk < 2; ++kk) {
                bf16x8 bfr[4];
                #pragma unroll
                for (int nf = 0; nf < 4; ++nf) {
                    int n = wn * 64 + nf * 16 + ml;
                    int s = (kk * 4 + q4) ^ (n & 7);
                    bfr[nf] = *(const bf16x8*)&cB[n * 64 + s * 8];
                }
                #pragma unroll
                for (int mf = 0; mf < 4; ++mf) {
                    int m = wm * 64 + mf * 16 + ml;
                    int s = (kk * 4 + q4) ^ (m & 7);
                    bf16x8 af = *(const bf16x8*)&cA[m * 64 + s * 8];
                    #pragma unroll
                    for (int nf = 0; nf < 4; ++nf)
                        acc[mf][nf] = __builtin_amdgcn_mfma_f32_16x16x32_bf16(
                            af, bfr[nf], acc[mf][nf], 0, 0, 0);
                }
            }
            __syncthreads();
        }
        #undef STAGE1

        // ---- fused per-row-chunk logsumexp partials (no logits write) -------
        int cj = bj >> 7;                // col-chunk 0..7
        float mloc[4][4], sloc[4][4];
        #pragma unroll
        for (int mf = 0; mf < 4; ++mf) {
            int rowb = bi + wm * 64 + mf * 16 + q4 * 4;
            float4 rnr = *(const float4*)&rnorm[rowb];
            #pragma unroll
            for (int i = 0; i < 4; ++i) {
                float mm = -1e30f;
                #pragma unroll
                for (int nf = 0; nf < 4; ++nf)
                    mm = fmaxf(mm, acc[mf][nf][i] * ((const float*)&rnr)[i]);
                mloc[mf][i] = mm;
            }
        }
        #pragma unroll
        for (int off = 1; off < 16; off <<= 1)
            #pragma unroll
            for (int mf = 0; mf < 4; ++mf)
                #pragma unroll
                for (int i = 0; i < 4; ++i)
                    mloc[mf][i] = fmaxf(mloc[mf][i], __shfl_xor(mloc[mf][i], off));
        #pragma unroll
        for (int mf = 0; mf < 4; ++mf) {
            int rowb = bi + wm * 64 + mf * 16 + q4 * 4;
            float4 rnr = *(const float4*)&rnorm[rowb];
            #pragma unroll
            for (int i = 0; i < 4; ++i) {
                float ss = 0.f;
                int row = rowb + i;
                #pragma unroll
                for (int nf = 0; nf < 4; ++nf) {
                    float v = acc[mf][nf][i] * ((const float*)&rnr)[i];
                    ss += expf(v - mloc[mf][i]);
                    int col = bj + wn * 64 + nf * 16 + ml;
                    if (col == (row >> 3)) g_diag[row] = v;
                }
                sloc[mf][i] = ss;
            }
        }
        #pragma unroll
        for (int off = 1; off < 16; off <<= 1)
            #pragma unroll
            for (int mf = 0; mf < 4; ++mf)
                #pragma unroll
                for (int i = 0; i < 4; ++i)
                    sloc[mf][i] += __shfl_xor(sloc[mf][i], off);
        float* s_m = (float*)smem;          // [256][2]
        float* s_s = s_m + 512;             // [256][2]
        if (ml == 0) {
            #pragma unroll
            for (int mf = 0; mf < 4; ++mf)
                #pragma unroll
                for (int i = 0; i < 4; ++i) {
                    int r = wm * 64 + mf * 16 + q4 * 4 + i;
                    s_m[r * 2 + wn] = mloc[mf][i];
                    s_s[r * 2 + wn] = sloc[mf][i];
                }
        }
        __syncthreads();
        if (t < 256) {
            float m0 = s_m[2 * t], m1 = s_m[2 * t + 1];
            float s0 = s_s[2 * t], s1 = s_s[2 * t + 1];
            float M = fmaxf(m0, m1);
            float S = s0 * expf(m0 - M) + s1 * expf(m1 - M);
            g_mx[(size_t)(bi + t) * 8 + cj] = M;
            g_se[(size_t)(bi + t) * 8 + cj] = S;
        }
    }
}

// ---- K3: finish-rowloss (2048) + regloss-combine (128), 256 thr -------------
__device__ inline void suffix_select1(unsigned* s_hist, unsigned kk,
                                      unsigned* s_wtot, unsigned* sh_bin,
                                      unsigned* sh_k, int t, int lane, int wid) {
    unsigned h = s_hist[t];
    unsigned v = h;
    #pragma unroll
    for (int off = 1; off < 64; off <<= 1) {
        unsigned o = __shfl_down(v, off);
        if (lane + off < 64) v += o;
    }
    if (lane == 0) s_wtot[wid] = v;
    __syncthreads();
    unsigned above = v - h;
    for (int w2 = wid + 1; w2 < 4; ++w2) above += s_wtot[w2];
    unsigned cum = above + h;
    if (cum >= kk && above < kk) { *sh_bin = (unsigned)t; *sh_k = kk - above; }
    __syncthreads();
}

__global__ __launch_bounds__(256) void k_finish(const int* __restrict__ target,
                                                const float* __restrict__ rowsig,
                                                const float* __restrict__ rnorm,
                                                const ushort_t* __restrict__ Abf,
                                                const ushort_t* __restrict__ Pbf,
                                                const float* __restrict__ g_cls,
                                                const float* __restrict__ g_bval,
                                                const ushort_t* __restrict__ g_bcol,
                                                const unsigned* __restrict__ g_cnt,
                                                const unsigned* __restrict__ g_ndef,
                                                const unsigned* __restrict__ g_flag,
                                                float* __restrict__ loss_part,
                                                const float* __restrict__ g_mx,
                                                const float* __restrict__ g_se,
                                                const float* __restrict__ g_diag,
                                                float* __restrict__ reg_part) {
    __shared__ __align__(16) unsigned char smem[16384];     // 16 KB union
    int bx = blockIdx.x, t = threadIdx.x;
    int lane = t & 63, wid = t >> 6;

    if (bx < 2048) {
        // ================= finish-rowloss: select band elems, softmax, loss ==
        float*    s_cls  = (float*)smem;                    // 1024 f
        float*    s_bval = (float*)(smem + 4096);           // 512 f
        ushort_t* s_bcol = (ushort_t*)(smem + 6144);        // 512 u16
        unsigned* s_hist = (unsigned*)(smem + 7168);        // 256 u32
        float*    s_arow = (float*)(smem + 8192);           // 512 f (fallback only)
        unsigned* s_wtot = (unsigned*)(smem + 10240);       // 4
        unsigned* shv    = (unsigned*)(smem + 10256);       // gc, bin, k
        float*    shf    = (float*)(smem + 10272);          // thr
        float*    red    = (float*)(smem + 10288);          // 4
        float*    s_gval = (float*)(smem + 10304);          // 64 f

        int b = bx;
        int tgt = target[b];
        float sig = rowsig[b] * (1.0f / 22.616f);
        float hiT = 1.80f * sig, loT = 1.47f * sig;
        float binscale = 256.0f / (hiT - loT);

        ((float4*)s_cls)[t] = ((const float4*)(g_cls + (size_t)b * C_CLS))[t];
        unsigned cnt = g_cnt[b], nd = g_ndef[b], fl = g_flag[b];
        int kq = (TOPK - NPROXY) - (int)nd;
        int ok = (fl == 0u) && (cnt <= ROW_CAP) && (kq >= 0) && ((int)cnt >= kq);
        if (t == 0) shv[0] = 0u;
        s_hist[t] = 0u;
        __syncthreads();

        if (ok) {
            if (kq > 0) {
                for (int j = t; j < (int)cnt; j += 256) {
                    float v = g_bval[(size_t)b * ROW_CAP + j];
                    s_bval[j] = v;
                    s_bcol[j] = g_bcol[(size_t)b * ROW_CAP + j];
                    int bin = (int)((v - loT) * binscale);
                    bin = (bin > 255) ? 255 : bin;
                    atomicAdd(&s_hist[bin], 1u);
                }
                __syncthreads();
                suffix_select1(s_hist, (unsigned)kq, s_wtot, &shv[1], &shv[2], t, lane, wid);
                int Bb = (int)shv[1];
                int knew = (int)shv[2];
                for (int j = t; j < (int)cnt; j += 256) {
                    float v = s_bval[j];
                    int bin = (int)((v - loT) * binscale);
                    bin = (bin > 255) ? 255 : bin;
                    if (bin == Bb) {
                        unsigned g = atomicAdd(&shv[0], 1u);
                        if (g < GCAP) s_gval[g] = v;
                    }
                }
                __syncthreads();
                int gc = (int)shv[0];
                if (gc <= GCAP) {
                    if (t < gc) {
                        float vj = s_gval[t];
                        unsigned g = 0, geq = 0;
                        for (int i = 0; i < gc; ++i) {
                            float vi = s_gval[i];
                            g   += (vi > vj) ? 1u : 0u;
                            geq += (vi >= vj) ? 1u : 0u;
                        }
                        if (g < (unsigned)knew && geq >= (unsigned)knew) shf[0] = vj;
                    }
                } else {
                    for (int j = t; j < (int)cnt; j += 256) {
                        float vj = s_bval[j];
                        unsigned g = 0, geq = 0;
                        for (int i = 0; i < (int)cnt; ++i) {
                            float vi = s_bval[i];
                            g   += (vi > vj) ? 1u : 0u;
                            geq += (vi >= vj) ? 1u : 0u;
                        }
                        if (g < (unsigned)kq && geq >= (unsigned)kq) shf[0] = vj;
                    }
                }
                __syncthreads();
                float thr = shf[0];
                for (int j = t; j < (int)cnt; j += 256)
                    if (s_bval[j] >= thr)
                        atomicAdd(&s_cls[s_bcol[j] >> 3], s_bval[j]);
            }
        } else {
            // exact fallback: recompute full sim row (never taken for this input)
            for (int i = t; i < DIM; i += 256)
                s_arow[i] = bf2f(Abf[(size_t)b * DIM + i]);
            #pragma unroll
            for (int i = 0; i < 4; ++i) s_cls[t + 256 * i] = 0.f;
            __syncthreads();
            float4 v4[8];
            for (int p = 0; p < 8; ++p) {
                int f = t + 256 * p;
                float vv[4];
                for (int e = 0; e < 4; ++e) {
                    int col = 4 * f + e;
                    const ushort_t* pc = Pbf + (size_t)col * DIM;
                    float a = 0.f;
                    for (int d = 0; d < DIM; ++d)
                        a += s_arow[d] * bf2f(pc[d]);
                    vv[e] = a * rnorm[col];
                }
                float4 o; o.x = vv[0]; o.y = vv[1]; o.z = vv[2]; o.w = vv[3];
                v4[p] = o;
            }
            #pragma unroll
            for (int p = 0; p < 8; ++p) {
                int f = t + 256 * p;
                const float* pv = (const float*)&v4[p];
                if ((f >> 1) == tgt)
                    atomicAdd(&s_cls[tgt], pv[0] + pv[1] + pv[2] + pv[3]);
            }
            unsigned L = 0u, R = 0xFFFFFFFFu;
            for (int it = 0; it < 33 && R - L > 1; ++it) {
                unsigned mid = L + ((R - L) >> 1);
                float c = 0.f;
                #pragma unroll
                for (int p = 0; p < 8; ++p) {
                    int f = t + 256 * p;
                    const float* pv = (const float*)&v4[p];
                    if ((f >> 1) != tgt) {
                        #pragma unroll
                        for (int e = 0; e < 4; ++e)
                            c += (f2ord(pv[e]) >= mid) ? 1.f : 0.f;
                    }
                }
                c = block_reduce(c, 0, red, t);
                if (c >= (float)(TOPK - NPROXY)) L = mid; else R = mid;
                __syncthreads();
            }
            #pragma unroll
            for (int p = 0; p < 8; ++p) {
                int f = t + 256 * p;
                const float* pv = (const float*)&v4[p];
                if ((f >> 1) != tgt) {
                    #pragma unroll
                    for (int e = 0; e < 4; ++e)
                        if (f2ord(pv[e]) >= L)
                            atomicAdd(&s_cls[f >> 1], pv[e]);
                }
            }
        }
        __syncthreads();

        float4 cv = ((const float4*)s_cls)[t];
        float m = -1e30f;
        if (cv.x != 0.0f) m = fmaxf(m, cv.x);
        if (cv.y != 0.0f) m = fmaxf(m, cv.y);
        if (cv.z != 0.0f) m = fmaxf(m, cv.z);
        if (cv.w != 0.0f) m = fmaxf(m, cv.w);
        m = block_reduce(m, 1, red, t);
        float se = 0.f;
        if (cv.x != 0.0f) se += expf(cv.x - m);
        if (cv.y != 0.0f) se += expf(cv.y - m);
        if (cv.z != 0.0f) se += expf(cv.z - m);
        if (cv.w != 0.0f) se += expf(cv.w - m);
        se = block_reduce(se, 0, red, t);
        if (t == 0) {
            float lt = s_cls[tgt];
            float predict_t = expf(lt - m) / (1e-8f * expf(-m) + se);
            loss_part[b] = -logf(predict_t + 1e-20f);
        }
    } else {
        // ================= regloss combine: 128 blocks x 64 rows =============
        float* red2 = (float*)smem;
        int rb = bx - 2048;
        float val = 0.f;
        if (t < 64) {
            int row = rb * 64 + t;
            float mj[8], sj[8];
            float M = -1e30f;
            #pragma unroll
            for (int j = 0; j < 8; ++j) {
                mj[j] = g_mx[(size_t)row * 8 + j];
                sj[j] = g_se[(size_t)row * 8 + j];
                M = fmaxf(M, mj[j]);
            }
            float S = 0.f;
            #pragma unroll
            for (int j = 0; j < 8; ++j) S += sj[j] * expf(mj[j] - M);
            val = M + logf(S) - g_diag[row];
        }
        val = block_reduce(val, 0, red2, t);
        if (t == 0) reg_part[rb] = val;
    }
}

// ---------------- K4: finalize (reduce 2048 + 128 partials) ------------------
__global__ __launch_bounds__(256) void k_final(const float* __restrict__ lp,
                                               const float* __restrict__ rp,
                                               float* __restrict__ out) {
    __shared__ float red[4];
    int t = threadIdx.x;
    float4 a = ((const float4*)lp)[t];
    float4 b = ((const float4*)lp)[t + 256];
    float ls = a.x + a.y + a.z + a.w + b.x + b.y + b.z + b.w;
    float rs = 0.f;
    if (t < 32) {
        float4 c = ((const float4*)rp)[t];
        rs = c.x + c.y + c.z + c.w;
    }
    ls = block_reduce(ls, 0, red, t);
    rs = block_reduce(rs, 0, red, t);
    if (t == 0) {
        float lc = ls / (float)BATCH;
        float rg = rs / (float)ALLNUM;
        out[0] = lc + LAM * rg;
        out[1] = lc;
    }
}

extern "C" void kernel_launch(void* const* d_in, const int* in_sizes, int n_in,
                              void* d_out, int out_size, void* d_ws, size_t ws_size,
                              hipStream_t stream) {
    const float* input  = (const float*)d_in[0];
    const int*   target = (const int*)d_in[1];
    const float* P      = (const float*)d_in[2];

    float* ws        = (float*)d_ws;
    float* rnorm     = ws + WS_RNORM;
    float* rowsig    = ws + WS_SIG;
    float* loss_part = ws + WS_LP;
    float* reg_part  = ws + WS_RP;
    unsigned* g_cnt  = (unsigned*)(ws + WS_CNT);
    unsigned* g_ndef = (unsigned*)(ws + WS_NDEF);
    unsigned* g_flag = (unsigned*)(ws + WS_FLAG);
    float* g_cls     = ws + WS_CLS;
    float* g_bval    = ws + WS_BVAL;
    ushort_t* g_bcol = (ushort_t*)(ws + WS_BCOL);
    ushort_t* Abf    = (ushort_t*)(ws + WS_ABF);
    ushort_t* Pbf    = (ushort_t*)(ws + WS_PBF);
    ushort_t* Stbf   = (ushort_t*)(ws + WS_STBF);
    float* g_mx      = ws + WS_MX;
    float* g_se      = ws + WS_SE;
    float* g_diag    = ws + WS_DIAG;
    float* out       = (float*)d_out;

    hipLaunchKernelGGL(k_prep1, dim3(256 + 1024 + 4096 + 1), dim3(256), 0, stream,
                       P, input, rnorm, rowsig, Abf, Pbf, Stbf, g_cnt);
    hipLaunchKernelGGL(k_gemms, dim3(512), dim3(512), 0, stream,
                       Abf, Pbf, Stbf, rnorm, rowsig, target,
                       g_cls, g_bval, g_bcol, g_cnt, g_ndef, g_flag,
                       g_mx, g_se, g_diag);
    hipLaunchKernelGGL(k_finish, dim3(2048 + 128), dim3(256), 0, stream,
                       target, rowsig, rnorm, Abf, Pbf,
                       g_cls, g_bval, g_bcol, g_cnt, g_ndef, g_flag,
                       loss_part, g_mx, g_se, g_diag, reg_part);
    hipLaunchKernelGGL(k_final, dim3(1), dim3(256), 0, stream,
                       loss_part, reg_part, out);
}